// Round 17
// baseline (210.686 us; speedup 1.0000x reference)
//
#include <hip/hip_runtime.h>
#include <hip/hip_bf16.h>

#define N_NODES 50000
#define E_EDGES 1600000
#define HID 128
#define NH 8
#define HD 16

#define NBKT 196        // ceil(50000/256) buckets of 256 dst nodes
#define BKT_CAP 9216    // mean 8192, sd ~90 -> +11 sigma headroom
#define CHUNK_A 4096
#define EPT 16          // edges per thread in binA (256 thr * 16)
#define BINA_BLOCKS ((E_EDGES + CHUNK_A - 1) / CHUNK_A)   // 391
#define WCVT_BLOCKS 771
#define LN_BLOCKS 12500
#define QKV_XBLOCKS ((N_NODES + 127) / 128)               // 391
#define ATTN_BLOCKS 2048
#define ATTN_WAVES (ATTN_BLOCKS * 4)                      // 8192

using short8 = __attribute__((ext_vector_type(8))) short;
using f32x4  = __attribute__((ext_vector_type(4))) float;
using f32x2  = __attribute__((ext_vector_type(2))) float;
typedef _Float16 h16x2 __attribute__((ext_vector_type(2)));

#if defined(__has_builtin) && __has_builtin(__builtin_amdgcn_fdot2)
#define FDOT2(a, b, c) __builtin_amdgcn_fdot2((a), (b), (c), false)
#else
__device__ __forceinline__ float FDOT2(h16x2 a, h16x2 b, float c) {
    return fmaf((float)a[0], (float)b[0], fmaf((float)a[1], (float)b[1], c));
}
#endif

__device__ __forceinline__ float wave_reduce_sum(float v) {
    #pragma unroll
    for (int off = 32; off > 0; off >>= 1) v += __shfl_xor(v, off, 64);
    return v;
}

__device__ __forceinline__ unsigned int packbf2(float a, float b) {
    __hip_bfloat162 t;
    t.x = __float2bfloat16(a);
    t.y = __float2bfloat16(b);
    unsigned int u;
    __builtin_memcpy(&u, &t, 4);
    return u;
}

__device__ __forceinline__ unsigned short bf16u(float v) {
    __hip_bfloat16 t = __float2bfloat16(v);
    unsigned short u;
    __builtin_memcpy(&u, &t, 2);
    return u;
}

__device__ __forceinline__ unsigned char fp8e(float v) {
    return (unsigned char)(__builtin_amdgcn_cvt_pk_fp8_f32(v, v, 0u, false) & 0xFFu);
}

union U4H {
    uint4 u;
    h16x2 h[4];
};

struct KV {
    U4H k0, k1;
    uint4 v;
};

__device__ __forceinline__ KV loadkv(const char* khs, const unsigned char* v8s, unsigned pk) {
    KV r;
    unsigned rr = pk & 0xFFFFu;
    r.k0.u = *(const uint4*)(khs + (rr << 8));
    r.k1.u = *(const uint4*)(khs + (rr << 8) + 16u);
    r.v = *(const uint4*)(v8s + (rr << 7));
    return r;
}

__device__ __forceinline__ void consume_kv(const KV& kv, unsigned pk, bool vd,
                                           const U4H& q0, const U4H& q1,
                                           const float* bLDS, int sub,
                                           f32x2* acc2, float& wsum) {
    float p = 0.f;
    #pragma unroll
    for (int j = 0; j < 4; ++j) p = FDOT2(q0.h[j], kv.k0.h[j], p);
    #pragma unroll
    for (int j = 0; j < 4; ++j) p = FDOT2(q1.h[j], kv.k1.h[j], p);
    float s = p + bLDS[((pk >> 16) & 0xFu) * 8 + sub];
    float w = vd ? __expf(s) : 0.f;
    wsum += w;
    f32x2 w2; w2[0] = w; w2[1] = w;
    f32x2 t;
    t = __builtin_amdgcn_cvt_pk_f32_fp8(kv.v.x, false); acc2[0] = t * w2 + acc2[0];
    t = __builtin_amdgcn_cvt_pk_f32_fp8(kv.v.x, true);  acc2[1] = t * w2 + acc2[1];
    t = __builtin_amdgcn_cvt_pk_f32_fp8(kv.v.y, false); acc2[2] = t * w2 + acc2[2];
    t = __builtin_amdgcn_cvt_pk_f32_fp8(kv.v.y, true);  acc2[3] = t * w2 + acc2[3];
    t = __builtin_amdgcn_cvt_pk_f32_fp8(kv.v.z, false); acc2[4] = t * w2 + acc2[4];
    t = __builtin_amdgcn_cvt_pk_f32_fp8(kv.v.z, true);  acc2[5] = t * w2 + acc2[5];
    t = __builtin_amdgcn_cvt_pk_f32_fp8(kv.v.w, false); acc2[6] = t * w2 + acc2[6];
    t = __builtin_amdgcn_cvt_pk_f32_fp8(kv.v.w, true);  acc2[7] = t * w2 + acc2[7];
}

// ================= prep kernel: binA + weight-convert + LN1 in one launch ==========
__global__ __launch_bounds__(256) void prep_kernel(
    const int* __restrict__ ei, const int* __restrict__ attr,
    int* __restrict__ bcur, unsigned int* __restrict__ temp,
    const float* __restrict__ Wq, const float* __restrict__ Wk,
    const float* __restrict__ Wv, const float* __restrict__ Wo,
    const float* __restrict__ W1, const float* __restrict__ W2,
    const float* __restrict__ bq, const float* __restrict__ bk,
    const float* __restrict__ bv,
    __hip_bfloat16* __restrict__ Wqkvt, __hip_bfloat16* __restrict__ Wot,
    __hip_bfloat16* __restrict__ W1t, __hip_bfloat16* __restrict__ W2t,
    float* __restrict__ bqkv,
    const float* __restrict__ x, const float* __restrict__ g1,
    const float* __restrict__ be1, __hip_bfloat16* __restrict__ h_out) {
    __shared__ unsigned int sval[CHUNK_A];
    __shared__ unsigned short sbkt[CHUNK_A];
    __shared__ int hist[NBKT];
    __shared__ int lofs[NBKT];
    __shared__ int gbase[NBKT];
    __shared__ int lcur[NBKT];
    __shared__ int sc[256];
    const int b = blockIdx.x;
    const int tid = threadIdx.x;
    if (b < BINA_BLOCKS) {
        const int e0 = b * CHUNK_A;
        const int n = min(CHUNK_A, E_EDGES - e0);
        for (int i = tid; i < NBKT; i += 256) hist[i] = 0;
        __syncthreads();
        unsigned int v[EPT];
        short bk_[EPT];
        #pragma unroll
        for (int j = 0; j < EPT; ++j) {
            int i = tid + j * 256;
            bk_[j] = -1;
            v[j] = 0;
            if (i < n) {
                int e = e0 + i;
                int src = ei[e];
                int dst = ei[E_EDGES + e];
                int a = attr[e]; a = min(max(a, 0), 12);
                v[j] = (unsigned)src | ((unsigned)a << 16) | ((unsigned)(dst & 255) << 20);
                int bb = dst >> 8;
                bk_[j] = (short)bb;
                atomicAdd(&hist[bb], 1);
            }
        }
        __syncthreads();
        sc[tid] = (tid < NBKT) ? hist[tid] : 0;
        __syncthreads();
        for (int off = 1; off < 256; off <<= 1) {
            int xx = (tid >= off) ? sc[tid - off] : 0;
            __syncthreads();
            sc[tid] += xx;
            __syncthreads();
        }
        if (tid < NBKT) {
            int h = hist[tid];
            lofs[tid] = sc[tid] - h;
            lcur[tid] = 0;
            gbase[tid] = h ? atomicAdd(&bcur[tid], h) : 0;
        }
        __syncthreads();
        #pragma unroll
        for (int j = 0; j < EPT; ++j) {
            if (bk_[j] >= 0) {
                int p = lofs[bk_[j]] + atomicAdd(&lcur[bk_[j]], 1);
                sval[p] = v[j];
                sbkt[p] = (unsigned short)bk_[j];
            }
        }
        __syncthreads();
        for (int i = tid; i < n; i += 256) {
            int bb = sbkt[i];
            temp[(size_t)bb * BKT_CAP + gbase[bb] + (i - lofs[bb])] = sval[i];
        }
    } else if (b < BINA_BLOCKS + WCVT_BLOCKS) {
        int t = (b - BINA_BLOCKS) * 256 + tid;
        if (t >= 196608) {
            int i = t - 196608;
            if (i < 384) bqkv[i] = i < 128 ? bq[i] : (i < 256 ? bk[i - 128] : bv[i - 256]);
            return;
        }
        const float* W; __hip_bfloat16* Wt; int K, N, idx;
        if (t < 65536) {
            int which = t >> 14; idx = t & 16383; K = 128; N = 128;
            W = which == 0 ? Wq : which == 1 ? Wk : which == 2 ? Wv : Wo;
            Wt = which == 3 ? Wot : Wqkvt + which * 16384;
        } else if (t < 131072) { idx = t - 65536;  K = 128; N = 512; W = W1; Wt = W1t; }
        else                   { idx = t - 131072; K = 512; N = 128; W = W2; Wt = W2t; }
        int n = idx / K, k = idx - n * K;
        Wt[idx] = __float2bfloat16(W[(size_t)k * N + n]);
    } else {
        int wave = tid >> 6;
        int lane = tid & 63;
        int row = (b - BINA_BLOCKS - WCVT_BLOCKS) * 4 + wave;
        if (row >= N_NODES) return;
        float2 v = ((const float2*)(x + (size_t)row * HID))[lane];
        float s = wave_reduce_sum(v.x + v.y);
        float mu = s * (1.0f / HID);
        float dx = v.x - mu, dy = v.y - mu;
        float q = wave_reduce_sum(dx * dx + dy * dy);
        float rstd = rsqrtf(q * (1.0f / HID) + 1e-5f);
        float2 gg = ((const float2*)g1)[lane];
        float2 bb = ((const float2*)be1)[lane];
        __hip_bfloat162 o;
        o.x = __float2bfloat16(dx * rstd * gg.x + bb.x);
        o.y = __float2bfloat16(dy * rstd * gg.y + bb.y);
        ((__hip_bfloat162*)(h_out + (size_t)row * HID))[lane] = o;
    }
}

// ================= merged kernel: binB (first 196 blocks) + QKV GEMM (rest) =========
__global__ __launch_bounds__(512) void qkv_binb_kernel(
    const int* __restrict__ bcur, const unsigned int* __restrict__ temp,
    unsigned int* __restrict__ packed, int* __restrict__ offs,
    const __hip_bfloat16* __restrict__ A, const __hip_bfloat16* __restrict__ Wt,
    const float* __restrict__ bias,
    _Float16* __restrict__ Chh, unsigned char* __restrict__ C8, int M) {
    __shared__ short8 smem[2048 + 2048];  // 64KB; binB aliases first 3KB
    const int tid = threadIdx.x;
    if (blockIdx.x < NBKT) {
        int* cnts = (int*)smem;
        int* hist = cnts + 256;
        int* cur = hist + 256;
        const int b = blockIdx.x;
        if (tid < 256) {
            cnts[tid] = (tid < NBKT) ? bcur[tid] : 0;
            hist[tid] = 0;
        }
        __syncthreads();
        for (int off = 1; off < 256; off <<= 1) {
            int x = 0;
            if (tid < 256 && tid >= off) x = cnts[tid - off];
            __syncthreads();
            if (tid < 256) cnts[tid] += x;
            __syncthreads();
        }
        const int cnt = bcur[b];
        const int start = cnts[b] - cnt;
        const size_t base = (size_t)b * BKT_CAP;
        for (int i = tid; i < cnt; i += 512)
            atomicAdd(&hist[(temp[base + i] >> 20) & 255], 1);
        __syncthreads();
        if (tid < 256) cur[tid] = hist[tid];
        __syncthreads();
        for (int off = 1; off < 256; off <<= 1) {
            int x = 0;
            if (tid < 256 && tid >= off) x = cur[tid - off];
            __syncthreads();
            if (tid < 256) cur[tid] += x;
            __syncthreads();
        }
        const int node0 = b * 256;
        if (tid < 256) {
            int excl = cur[tid] - hist[tid];
            cur[tid] = excl;
            int node = node0 + tid;
            if (node < N_NODES) offs[node] = start + excl;
        }
        if (b == NBKT - 1 && tid == 0) offs[N_NODES] = start + cnt;
        __syncthreads();
        for (int i = tid; i < cnt; i += 512) {
            unsigned int v = temp[base + i];
            int d = (v >> 20) & 255;
            int p = start + atomicAdd(&cur[d], 1);
            packed[p] = v & 0xFFFFFu;   // src | attr<<16
        }
        return;
    }
    // ---- QKV GEMM part ----
    const int gb = blockIdx.x - NBKT;
    const int plane = gb / QKV_XBLOCKS;
    const int xb = gb - plane * QKV_XBLOCKS;
    const int row0 = xb * 128;
    const int col0 = plane * 128;
    const int w = tid >> 6, l = tid & 63;
    const int lr = l & 15, hi = l >> 4;
    f32x4 acc[8] = {};
    #pragma unroll
    for (int it = 0; it < 4; ++it) {
        unsigned d = tid + it * 512;
        int r = d >> 4, sd = d & 15;
        int ss = sd ^ (r & 7);
        int gr = row0 + r; if (gr >= M) gr = M - 1;
        __builtin_amdgcn_global_load_lds(
            (const __attribute__((address_space(1))) void*)(A + (size_t)gr * 128 + ss * 8),
            (__attribute__((address_space(3))) void*)(smem + (d & ~63u)),
            16, 0, 0);
    }
    #pragma unroll
    for (int it = 0; it < 4; ++it) {
        unsigned d = tid + it * 512;
        int r = d >> 4, sd = d & 15;
        int ss = sd ^ (r & 7);
        __builtin_amdgcn_global_load_lds(
            (const __attribute__((address_space(1))) void*)(Wt + (size_t)(col0 + r) * 128 + ss * 8),
            (__attribute__((address_space(3))) void*)(smem + 2048 + (d & ~63u)),
            16, 0, 0);
    }
    __syncthreads();
    const int ar = w * 16 + lr;
    #pragma unroll
    for (int ks = 0; ks < 4; ++ks) {
        int s = ks * 4 + hi;
        short8 a = smem[ar * 16 + (s ^ (ar & 7))];
        #pragma unroll
        for (int f = 0; f < 8; ++f) {
            int br = f * 16 + lr;
            short8 b = smem[2048 + br * 16 + (s ^ (br & 7))];
            acc[f] = __builtin_amdgcn_mfma_f32_16x16x32_bf16(a, b, acc[f], 0, 0, 0);
        }
    }
    const float scl = (plane == 0) ? 0.25f : 1.0f;
    #pragma unroll
    for (int f = 0; f < 8; ++f) {
        int c = col0 + f * 16 + lr;
        float bv = bias[c];
        #pragma unroll
        for (int j = 0; j < 4; ++j) {
            int r = row0 + w * 16 + hi * 4 + j;
            if (r < M) {
                float v = acc[f][j] + bv;
                if (plane < 2)
                    Chh[(size_t)plane * N_NODES * 128 + (size_t)r * 128 + (c & 127)] =
                        (_Float16)(v * scl);
                else
                    C8[(size_t)r * 128 + (c & 127)] = fp8e(v);
            }
        }
    }
}

// ===== Fused tail: Wo GEMM + residual(x) + LN2 + FFN1 + relu + FFN2 + residual =====
// 32 rows/block, 256 thr (4 waves). Wave w: rt=w&1 (16-row half), ch=w>>1 (64-col half).
// hseg: attn_ob tile then h2 tile (8KB). wseg: Wot then f1 tile (32KB).
// bseg: DOUBLE-BUFFERED 2x16KB weight staging (stage c+1 overlaps compute c, 1 barrier/chunk).
// x1 kept in REGISTERS (f32) for the final residual.
__global__ __launch_bounds__(256) void tail_kernel(
    const __hip_bfloat16* __restrict__ attn_ob,  // [N][128]
    const __hip_bfloat16* __restrict__ Wot,      // [128][128]
    const float* __restrict__ bo,
    const float* __restrict__ x,                 // [N][128] f32
    const float* __restrict__ g2, const float* __restrict__ be2,
    const __hip_bfloat16* __restrict__ W1t,      // [512][128]
    const float* __restrict__ b1,
    const __hip_bfloat16* __restrict__ W2t,      // [128][512]
    const float* __restrict__ b2,
    float* __restrict__ outp, int M) {
    __shared__ short8 hseg[32 * 16];     // 8KB
    __shared__ short8 wseg[2048];        // 32KB
    __shared__ short8 bseg[2][1024];     // 2x16KB double buffer
    __shared__ float lnS[2][32];
    __shared__ float lnQ[2][32];
    const int tid = threadIdx.x;
    const int row0 = blockIdx.x * 32;
    const int w = tid >> 6, l = tid & 63;
    const int lr = l & 15, hi = l >> 4;
    const int rt = w & 1, ch = w >> 1;
    // stage attn_ob tile (512 segs)
    #pragma unroll
    for (int it = 0; it < 2; ++it) {
        unsigned d = tid + it * 256;
        int r = d >> 4, sd = d & 15;
        int ss = sd ^ (r & 7);
        int gr = row0 + r; if (gr >= M) gr = M - 1;
        __builtin_amdgcn_global_load_lds(
            (const __attribute__((address_space(1))) void*)(attn_ob + (size_t)gr * 128 + ss * 8),
            (__attribute__((address_space(3))) void*)(hseg + (d & ~63u)),
            16, 0, 0);
    }
    // stage Wot (2048 segs)
    #pragma unroll
    for (int it = 0; it < 8; ++it) {
        unsigned d = tid + it * 256;
        int r = d >> 4, sd = d & 15;
        int ss = sd ^ (r & 7);
        __builtin_amdgcn_global_load_lds(
            (const __attribute__((address_space(1))) void*)(Wot + (size_t)r * 128 + ss * 8),
            (__attribute__((address_space(3))) void*)(wseg + (d & ~63u)),
            16, 0, 0);
    }
    // prefetch FFN1 chunk 0 into bseg[0]
    #pragma unroll
    for (int it = 0; it < 4; ++it) {
        unsigned d = tid + it * 256;
        int rb = d >> 4, sd = d & 15;
        int ss = sd ^ (rb & 7);
        __builtin_amdgcn_global_load_lds(
            (const __attribute__((address_space(1))) void*)(W1t + (size_t)rb * 128 + ss * 8),
            (__attribute__((address_space(3))) void*)(bseg[0] + (d & ~63u)),
            16, 0, 0);
    }
    __syncthreads();
    // Wo GEMM: wave covers rows rt*16..+15, cols ch*64..+63
    const int ar = rt * 16 + lr;
    f32x4 acc[4] = {};
    #pragma unroll
    for (int ks = 0; ks < 4; ++ks) {
        int s = ks * 4 + hi;
        short8 a = hseg[ar * 16 + (s ^ (ar & 7))];
        #pragma unroll
        for (int f = 0; f < 4; ++f) {
            int br = ch * 64 + f * 16 + lr;
            short8 b = wseg[br * 16 + (s ^ (br & 7))];
            acc[f] = __builtin_amdgcn_mfma_f32_16x16x32_bf16(a, b, acc[f], 0, 0, 0);
        }
    }
    // x1 = acc + bo + x residual (kept in registers)
    float vv[4][4];
    float gc[4], bc[4];
    #pragma unroll
    for (int f = 0; f < 4; ++f) {
        int c = ch * 64 + f * 16 + lr;
        gc[f] = g2[c]; bc[f] = be2[c];
        float bv = bo[c];
        #pragma unroll
        for (int j = 0; j < 4; ++j) {
            int r = row0 + rt * 16 + hi * 4 + j;
            int rr = r < M ? r : M - 1;
            vv[f][j] = acc[f][j] + bv + x[(size_t)rr * 128 + c];
        }
    }
    // LN2 partials over this wave's 64 cols
    float ps[4], pq[4];
    #pragma unroll
    for (int j = 0; j < 4; ++j) {
        float s = 0.f, q = 0.f;
        #pragma unroll
        for (int f = 0; f < 4; ++f) { s += vv[f][j]; q += vv[f][j] * vv[f][j]; }
        #pragma unroll
        for (int m = 1; m <= 8; m <<= 1) { s += __shfl_xor(s, m); q += __shfl_xor(q, m); }
        ps[j] = s; pq[j] = q;
    }
    if (lr == 0) {
        #pragma unroll
        for (int j = 0; j < 4; ++j) {
            int r = rt * 16 + hi * 4 + j;
            lnS[ch][r] = ps[j];
            lnQ[ch][r] = pq[j];
        }
    }
    __syncthreads();
    // combine halves; write h2 bf16 into hseg (overwrites attn_ob tile)
    unsigned short* hu = (unsigned short*)hseg;
    #pragma unroll
    for (int j = 0; j < 4; ++j) {
        int r = rt * 16 + hi * 4 + j;
        float s = lnS[0][r] + lnS[1][r];
        float q = lnQ[0][r] + lnQ[1][r];
        float mu = s * (1.0f / 128.0f);
        float rstd = rsqrtf(q * (1.0f / 128.0f) - mu * mu + 1e-5f);
        #pragma unroll
        for (int f = 0; f < 4; ++f) {
            int c = ch * 64 + f * 16 + lr;
            int seg = c >> 3;
            float hv = (vv[f][j] - mu) * rstd * gc[f] + bc[f];
            hu[r * 128 + ((seg ^ (r & 7)) << 3) + (c & 7)] = bf16u(hv);
        }
    }
    __syncthreads();
    // FFN1: 8 chunks of 64 out-cols; f1 tile into wseg (Wot dead).
    // Pipeline: stage(c+1) issued before compute(c); single barrier per chunk.
    unsigned short* f1u = (unsigned short*)wseg;
    for (int cc = 0; cc < 8; ++cc) {
        if (cc + 1 < 8) {
            short8* dst = bseg[(cc + 1) & 1];
            #pragma unroll
            for (int it = 0; it < 4; ++it) {
                unsigned d = tid + it * 256;
                int rb = d >> 4, sd = d & 15;
                int ss = sd ^ (rb & 7);
                __builtin_amdgcn_global_load_lds(
                    (const __attribute__((address_space(1))) void*)(W1t + (size_t)((cc + 1) * 64 + rb) * 128 + ss * 8),
                    (__attribute__((address_space(3))) void*)(dst + (d & ~63u)),
                    16, 0, 0);
            }
        } else {
            // prefetch FFN2 chunk 0 into bseg[0] (bseg[0] last read at cc=6; barrier since)
            #pragma unroll
            for (int it = 0; it < 4; ++it) {
                unsigned d = tid + it * 256;
                int rb = d >> 3, sd = d & 7;
                int ss = sd ^ (rb & 7);
                __builtin_amdgcn_global_load_lds(
                    (const __attribute__((address_space(1))) void*)(W2t + (size_t)rb * 512 + ss * 8),
                    (__attribute__((address_space(3))) void*)(bseg[0] + (d & ~63u)),
                    16, 0, 0);
            }
        }
        const short8* cur = bseg[cc & 1];
        f32x4 a0 = {}, a1 = {};
        #pragma unroll
        for (int ks = 0; ks < 4; ++ks) {
            int s = ks * 4 + hi;
            short8 a = hseg[ar * 16 + (s ^ (ar & 7))];
            int rb0 = ch * 32 + lr;
            short8 b0 = cur[rb0 * 16 + (s ^ (rb0 & 7))];
            a0 = __builtin_amdgcn_mfma_f32_16x16x32_bf16(a, b0, a0, 0, 0, 0);
            int rb1 = ch * 32 + 16 + lr;
            short8 b1v = cur[rb1 * 16 + (s ^ (rb1 & 7))];
            a1 = __builtin_amdgcn_mfma_f32_16x16x32_bf16(a, b1v, a1, 0, 0, 0);
        }
        #pragma unroll
        for (int f = 0; f < 2; ++f) {
            int c = cc * 64 + ch * 32 + f * 16 + lr;    // 0..511
            float bv = b1[c];
            int seg = c >> 3;
            #pragma unroll
            for (int j = 0; j < 4; ++j) {
                int r = rt * 16 + hi * 4 + j;
                float v = fmaxf((f == 0 ? a0[j] : a1[j]) + bv, 0.f);
                f1u[r * 512 + ((seg ^ (r & 7)) << 3) + (c & 7)] = bf16u(v);
            }
        }
        __syncthreads();   // next buf loads done + f1 writes visible
    }
    // FFN2: K=512 in 8 chunks of 64; same pipeline.
    f32x4 acc2[4] = {};
    for (int kc = 0; kc < 8; ++kc) {
        if (kc + 1 < 8) {
            short8* dst = bseg[(kc + 1) & 1];
            #pragma unroll
            for (int it = 0; it < 4; ++it) {
                unsigned d = tid + it * 256;
                int rb = d >> 3, sd = d & 7;
                int ss = sd ^ (rb & 7);
                __builtin_amdgcn_global_load_lds(
                    (const __attribute__((address_space(1))) void*)(W2t + (size_t)rb * 512 + (kc + 1) * 64 + ss * 8),
                    (__attribute__((address_space(3))) void*)(dst + (d & ~63u)),
                    16, 0, 0);
            }
        }
        const short8* cur = bseg[kc & 1];
        #pragma unroll
        for (int ks = 0; ks < 2; ++ks) {
            int ksg = kc * 8 + ks * 4 + hi;             // global k-seg 0..63
            short8 a = *(const short8*)&f1u[ar * 512 + ((ksg ^ (ar & 7)) << 3)];
            int s2 = ks * 4 + hi;
            #pragma unroll
            for (int f = 0; f < 4; ++f) {
                int rb = ch * 64 + f * 16 + lr;
                short8 b = cur[rb * 8 + (s2 ^ (rb & 7))];
                acc2[f] = __builtin_amdgcn_mfma_f32_16x16x32_bf16(a, b, acc2[f], 0, 0, 0);
            }
        }
        __syncthreads();
    }
    // epilogue: + b2 + x1 (register, f32) -> out
    #pragma unroll
    for (int f = 0; f < 4; ++f) {
        int c = ch * 64 + f * 16 + lr;
        float bv = b2[c];
        #pragma unroll
        for (int j = 0; j < 4; ++j) {
            int r = row0 + rt * 16 + hi * 4 + j;
            if (r < M)
                outp[(size_t)r * 128 + c] = acc2[f][j] + bv + vv[f][j];
        }
    }
}

// ---------------- Fused edge phase: persistent waves, EDGE-BALANCED partition ------
// Q,K: f16 planes [2][N][128] (Q pre-scaled 1/sqrt(D)); V: fp8 plane [N][128].
// Wave wid binary-searches offs for its equal-edge node range [n0,n1) -> no
// degree-tail or quantization drain. Per-node math identical (bit-for-bit).
__global__ __launch_bounds__(256) void fused_attn_kernel(
    const unsigned int* __restrict__ packed,
    const int* __restrict__ offs,
    const _Float16* __restrict__ qkh,   // [2][N][128]
    const unsigned char* __restrict__ v8p,  // [N][128]
    const float* __restrict__ btab,     // [13,8]
    __hip_bfloat16* __restrict__ out) {
    __shared__ float bLDS[104];
    const int tid = threadIdx.x;
    if (tid < 104) bLDS[tid] = btab[tid];
    __syncthreads();
    const int wave = tid >> 6, lane = tid & 63;
    const int slot = lane >> 3, sub = lane & 7;
    const char* qh = (const char*)qkh;
    const unsigned sb = (unsigned)sub << 5;
    const char* khs = (const char*)(qkh + (size_t)N_NODES * 128) + sb;
    const unsigned char* v8s = v8p + (sb >> 1);
    const unsigned wid = blockIdx.x * 4 + wave;
    // edge-balanced node range: n0 = lb(wid*E/NW), n1 = lb((wid+1)*E/NW)
    long long t0 = (long long)E_EDGES * wid / ATTN_WAVES;
    long long t1 = (long long)E_EDGES * (wid + 1) / ATTN_WAVES;
    int lo_ = 0, hi_ = N_NODES;
    while (lo_ < hi_) { int mid = (lo_ + hi_) >> 1; if ((long long)offs[mid] < t0) lo_ = mid + 1; else hi_ = mid; }
    const int n0 = lo_;
    lo_ = n0; hi_ = N_NODES;
    while (lo_ < hi_) { int mid = (lo_ + hi_) >> 1; if ((long long)offs[mid] < t1) lo_ = mid + 1; else hi_ = mid; }
    int n1 = lo_;
    if (wid == ATTN_WAVES - 1) n1 = N_NODES;   // include zero-degree stragglers
    for (int n = n0; n < n1; ++n) {
        U4H q0, q1;
        q0.u = *(const uint4*)(qh + ((unsigned)n << 8) + sb);
        q1.u = *(const uint4*)(qh + ((unsigned)n << 8) + sb + 16u);
        const int lo = offs[n], hi = offs[n + 1];
        const int nit = (hi - lo + 7) >> 3;
        f32x2 acc2[8] = {};
        float wsum = 0.f;
        int i = lo + slot;
        bool vd0 = i < hi;       unsigned pk0 = vd0 ? packed[i] : 0u;
        bool vd1 = i + 8 < hi;   unsigned pk1 = vd1 ? packed[i + 8] : 0u;
        KV a = loadkv(khs, v8s, pk0);
        KV b = loadkv(khs, v8s, pk1);
        int ii = i + 16;
        int rem = nit;
        while (rem >= 2) {
            const bool vd2 = ii < hi;
            const unsigned pk2 = vd2 ? packed[ii] : 0u;
            const bool vd3 = ii + 8 < hi;
            const unsigned pk3 = vd3 ? packed[ii + 8] : 0u;
            consume_kv(a, pk0, vd0, q0, q1, bLDS, sub, acc2, wsum);
            a = loadkv(khs, v8s, pk2);
            consume_kv(b, pk1, vd1, q0, q1, bLDS, sub, acc2, wsum);
            b = loadkv(khs, v8s, pk3);
            pk0 = pk2; vd0 = vd2;
            pk1 = pk3; vd1 = vd3;
            ii += 16;
            rem -= 2;
        }
        if (rem == 1) consume_kv(a, pk0, vd0, q0, q1, bLDS, sub, acc2, wsum);
        float accf[16];
        #pragma unroll
        for (int j = 0; j < 8; ++j) { accf[2 * j] = acc2[j][0]; accf[2 * j + 1] = acc2[j][1]; }
        #pragma unroll
        for (int j = 0; j < 16; ++j) {
            accf[j] += __shfl_xor(accf[j], 8);
            accf[j] += __shfl_xor(accf[j], 16);
            accf[j] += __shfl_xor(accf[j], 32);
        }
        wsum += __shfl_xor(wsum, 8);
        wsum += __shfl_xor(wsum, 16);
        wsum += __shfl_xor(wsum, 32);
        if (slot == 0) {
            float inv = 1.0f / (wsum + 1e-8f);
            uint4 o0, o1;
            o0.x = packbf2(accf[0] * inv, accf[1] * inv);
            o0.y = packbf2(accf[2] * inv, accf[3] * inv);
            o0.z = packbf2(accf[4] * inv, accf[5] * inv);
            o0.w = packbf2(accf[6] * inv, accf[7] * inv);
            o1.x = packbf2(accf[8] * inv, accf[9] * inv);
            o1.y = packbf2(accf[10] * inv, accf[11] * inv);
            o1.z = packbf2(accf[12] * inv, accf[13] * inv);
            o1.w = packbf2(accf[14] * inv, accf[15] * inv);
            char* op = (char*)out + ((unsigned)n << 8) + ((unsigned)sub << 5);
            *(uint4*)op = o0;
            *(uint4*)(op + 16) = o1;
        }
    }
}

extern "C" void kernel_launch(void* const* d_in, const int* in_sizes, int n_in,
                              void* d_out, int out_size, void* d_ws, size_t ws_size,
                              hipStream_t stream) {
    const float* x    = (const float*)d_in[0];
    const int*   ei   = (const int*)d_in[1];
    const int*   attr = (const int*)d_in[2];
    const float* Wq   = (const float*)d_in[3];
    const float* bq   = (const float*)d_in[4];
    const float* Wk   = (const float*)d_in[5];
    const float* bk   = (const float*)d_in[6];
    const float* Wv   = (const float*)d_in[7];
    const float* bv   = (const float*)d_in[8];
    const float* Wo   = (const float*)d_in[9];
    const float* bo   = (const float*)d_in[10];
    const float* ebt  = (const float*)d_in[11];
    const float* W1   = (const float*)d_in[12];
    const float* b1   = (const float*)d_in[13];
    const float* W2   = (const float*)d_in[14];
    const float* b2   = (const float*)d_in[15];
    const float* g1   = (const float*)d_in[16];
    const float* be1  = (const float*)d_in[17];
    const float* g2   = (const float*)d_in[18];
    const float* be2  = (const float*)d_in[19];
    float* out = (float*)d_out;

    char* ws = (char*)d_ws;
    const size_t szRowB = (size_t)N_NODES * HID * 2;   // 12.8 MB
    const size_t ALIGN = 256;
    #define ALN(v) (((v) + ALIGN - 1) & ~(ALIGN - 1))
    size_t o = 0;
    __hip_bfloat16* h_buf = (__hip_bfloat16*)(ws + o); o += szRowB;
    _Float16* QKh = (_Float16*)(ws + o); o += (size_t)N_NODES * 256 * 2;        // 25.6MB (Q+K f16)
    unsigned char* V8 = (unsigned char*)(ws + o); o += (size_t)N_NODES * 128;   // 6.4MB
    unsigned int* packed = (unsigned int*)(ws + o); o += (size_t)E_EDGES * 4;   // 6.4MB
    unsigned int* temp = (unsigned int*)(ws + o); o += (size_t)NBKT * BKT_CAP * 4; // 7.2MB
    int* bcur = (int*)(ws + o); o = ALN(o + (size_t)NBKT * 4);
    int* offs = (int*)(ws + o); o = ALN(o + (size_t)(N_NODES + 1) * 4);
    __hip_bfloat16* attn_ob = (__hip_bfloat16*)(ws + o); o += szRowB;
    __hip_bfloat16* Wqkvt = (__hip_bfloat16*)(ws + o); o += 384 * 128 * 2;
    __hip_bfloat16* Wot = (__hip_bfloat16*)(ws + o); o += 128 * 128 * 2;
    __hip_bfloat16* W1t = (__hip_bfloat16*)(ws + o); o += 512 * 128 * 2;
    __hip_bfloat16* W2t = (__hip_bfloat16*)(ws + o); o += 128 * 512 * 2;
    float* bqkv = (float*)(ws + o); o += 384 * 4;       // ~60 MB total

    hipMemsetAsync(bcur, 0, (size_t)NBKT * 4, stream);

    // Stage 1: binA + weight converts + LN1 co-scheduled in one launch
    prep_kernel<<<BINA_BLOCKS + WCVT_BLOCKS + LN_BLOCKS, 256, 0, stream>>>(
        ei, attr, bcur, temp,
        Wq, Wk, Wv, Wo, W1, W2, bq, bk, bv,
        Wqkvt, Wot, W1t, W2t, bqkv,
        x, g1, be1, h_buf);

    // Stage 2: binB (196 blocks) + QKV GEMM (391x3 blocks) in one launch
    qkv_binb_kernel<<<NBKT + QKV_XBLOCKS * 3, 512, 0, stream>>>(
        bcur, temp, packed, offs,
        h_buf, Wqkvt, bqkv, QKh, V8, N_NODES);

    // Fused edge phase: edge-balanced persistent waves; Q/K f16, V fp8
    fused_attn_kernel<<<ATTN_BLOCKS, 256, 0, stream>>>(packed, offs, QKh, V8, ebt, attn_ob);

    // Fused tail: Wo + residual + LN2 + FFN1 + FFN2 + residual, one kernel (dbuf staging)
    tail_kernel<<<(N_NODES + 31) / 32, 256, 0, stream>>>(
        attn_ob, Wot, bo, x, g2, be2, W1t, b1, W2t, b2, out, N_NODES);
}

// Round 18
// 196.094 us; speedup vs baseline: 1.0744x; 1.0744x over previous
//
#include <hip/hip_runtime.h>
#include <hip/hip_bf16.h>

#define N_NODES 50000
#define E_EDGES 1600000
#define HID 128
#define NH 8
#define HD 16

#define NBKT 196        // ceil(50000/256) buckets of 256 dst nodes
#define BKT_CAP 9216    // mean 8192, sd ~90 -> +11 sigma headroom
#define CHUNK_A 4096
#define EPT 16          // edges per thread in binA (256 thr * 16)
#define BINA_BLOCKS ((E_EDGES + CHUNK_A - 1) / CHUNK_A)   // 391
#define WCVT_BLOCKS 771
#define LN_BLOCKS 12500
#define QKV_XBLOCKS ((N_NODES + 127) / 128)               // 391
#define ATTN_BLOCKS 2048

using short8 = __attribute__((ext_vector_type(8))) short;
using f32x4  = __attribute__((ext_vector_type(4))) float;
using f32x2  = __attribute__((ext_vector_type(2))) float;
typedef _Float16 h16x2 __attribute__((ext_vector_type(2)));

#if defined(__has_builtin) && __has_builtin(__builtin_amdgcn_fdot2)
#define FDOT2(a, b, c) __builtin_amdgcn_fdot2((a), (b), (c), false)
#else
__device__ __forceinline__ float FDOT2(h16x2 a, h16x2 b, float c) {
    return fmaf((float)a[0], (float)b[0], fmaf((float)a[1], (float)b[1], c));
}
#endif

__device__ __forceinline__ float wave_reduce_sum(float v) {
    #pragma unroll
    for (int off = 32; off > 0; off >>= 1) v += __shfl_xor(v, off, 64);
    return v;
}

__device__ __forceinline__ unsigned int packbf2(float a, float b) {
    __hip_bfloat162 t;
    t.x = __float2bfloat16(a);
    t.y = __float2bfloat16(b);
    unsigned int u;
    __builtin_memcpy(&u, &t, 4);
    return u;
}

__device__ __forceinline__ unsigned short bf16u(float v) {
    __hip_bfloat16 t = __float2bfloat16(v);
    unsigned short u;
    __builtin_memcpy(&u, &t, 2);
    return u;
}

__device__ __forceinline__ unsigned char fp8e(float v) {
    return (unsigned char)(__builtin_amdgcn_cvt_pk_fp8_f32(v, v, 0u, false) & 0xFFu);
}

union U4H {
    uint4 u;
    h16x2 h[4];
};

struct KV {
    U4H k0, k1;
    uint4 v;
};

__device__ __forceinline__ KV loadkv(const char* khs, const unsigned char* v8s, unsigned pk) {
    KV r;
    unsigned rr = pk & 0xFFFFu;
    r.k0.u = *(const uint4*)(khs + (rr << 8));
    r.k1.u = *(const uint4*)(khs + (rr << 8) + 16u);
    r.v = *(const uint4*)(v8s + (rr << 7));
    return r;
}

__device__ __forceinline__ void consume_kv(const KV& kv, unsigned pk, bool vd,
                                           const U4H& q0, const U4H& q1,
                                           const float* bLDS, int sub,
                                           f32x2* acc2, float& wsum) {
    float p = 0.f;
    #pragma unroll
    for (int j = 0; j < 4; ++j) p = FDOT2(q0.h[j], kv.k0.h[j], p);
    #pragma unroll
    for (int j = 0; j < 4; ++j) p = FDOT2(q1.h[j], kv.k1.h[j], p);
    float s = p + bLDS[((pk >> 16) & 0xFu) * 8 + sub];
    float w = vd ? __expf(s) : 0.f;
    wsum += w;
    f32x2 w2; w2[0] = w; w2[1] = w;
    f32x2 t;
    t = __builtin_amdgcn_cvt_pk_f32_fp8(kv.v.x, false); acc2[0] = t * w2 + acc2[0];
    t = __builtin_amdgcn_cvt_pk_f32_fp8(kv.v.x, true);  acc2[1] = t * w2 + acc2[1];
    t = __builtin_amdgcn_cvt_pk_f32_fp8(kv.v.y, false); acc2[2] = t * w2 + acc2[2];
    t = __builtin_amdgcn_cvt_pk_f32_fp8(kv.v.y, true);  acc2[3] = t * w2 + acc2[3];
    t = __builtin_amdgcn_cvt_pk_f32_fp8(kv.v.z, false); acc2[4] = t * w2 + acc2[4];
    t = __builtin_amdgcn_cvt_pk_f32_fp8(kv.v.z, true);  acc2[5] = t * w2 + acc2[5];
    t = __builtin_amdgcn_cvt_pk_f32_fp8(kv.v.w, false); acc2[6] = t * w2 + acc2[6];
    t = __builtin_amdgcn_cvt_pk_f32_fp8(kv.v.w, true);  acc2[7] = t * w2 + acc2[7];
}

// ================= prep kernel: binA + weight-convert + LN1 in one launch ==========
__global__ __launch_bounds__(256) void prep_kernel(
    const int* __restrict__ ei, const int* __restrict__ attr,
    int* __restrict__ bcur, unsigned int* __restrict__ temp,
    const float* __restrict__ Wq, const float* __restrict__ Wk,
    const float* __restrict__ Wv, const float* __restrict__ Wo,
    const float* __restrict__ W1, const float* __restrict__ W2,
    const float* __restrict__ bq, const float* __restrict__ bk,
    const float* __restrict__ bv,
    __hip_bfloat16* __restrict__ Wqkvt, __hip_bfloat16* __restrict__ Wot,
    __hip_bfloat16* __restrict__ W1t, __hip_bfloat16* __restrict__ W2t,
    float* __restrict__ bqkv,
    const float* __restrict__ x, const float* __restrict__ g1,
    const float* __restrict__ be1, __hip_bfloat16* __restrict__ h_out) {
    __shared__ unsigned int sval[CHUNK_A];
    __shared__ unsigned short sbkt[CHUNK_A];
    __shared__ int hist[NBKT];
    __shared__ int lofs[NBKT];
    __shared__ int gbase[NBKT];
    __shared__ int lcur[NBKT];
    __shared__ int sc[256];
    const int b = blockIdx.x;
    const int tid = threadIdx.x;
    if (b < BINA_BLOCKS) {
        const int e0 = b * CHUNK_A;
        const int n = min(CHUNK_A, E_EDGES - e0);
        for (int i = tid; i < NBKT; i += 256) hist[i] = 0;
        __syncthreads();
        unsigned int v[EPT];
        short bk_[EPT];
        #pragma unroll
        for (int j = 0; j < EPT; ++j) {
            int i = tid + j * 256;
            bk_[j] = -1;
            v[j] = 0;
            if (i < n) {
                int e = e0 + i;
                int src = ei[e];
                int dst = ei[E_EDGES + e];
                int a = attr[e]; a = min(max(a, 0), 12);
                v[j] = (unsigned)src | ((unsigned)a << 16) | ((unsigned)(dst & 255) << 20);
                int bb = dst >> 8;
                bk_[j] = (short)bb;
                atomicAdd(&hist[bb], 1);
            }
        }
        __syncthreads();
        sc[tid] = (tid < NBKT) ? hist[tid] : 0;
        __syncthreads();
        for (int off = 1; off < 256; off <<= 1) {
            int xx = (tid >= off) ? sc[tid - off] : 0;
            __syncthreads();
            sc[tid] += xx;
            __syncthreads();
        }
        if (tid < NBKT) {
            int h = hist[tid];
            lofs[tid] = sc[tid] - h;
            lcur[tid] = 0;
            gbase[tid] = h ? atomicAdd(&bcur[tid], h) : 0;
        }
        __syncthreads();
        #pragma unroll
        for (int j = 0; j < EPT; ++j) {
            if (bk_[j] >= 0) {
                int p = lofs[bk_[j]] + atomicAdd(&lcur[bk_[j]], 1);
                sval[p] = v[j];
                sbkt[p] = (unsigned short)bk_[j];
            }
        }
        __syncthreads();
        for (int i = tid; i < n; i += 256) {
            int bb = sbkt[i];
            temp[(size_t)bb * BKT_CAP + gbase[bb] + (i - lofs[bb])] = sval[i];
        }
    } else if (b < BINA_BLOCKS + WCVT_BLOCKS) {
        int t = (b - BINA_BLOCKS) * 256 + tid;
        if (t >= 196608) {
            int i = t - 196608;
            if (i < 384) bqkv[i] = i < 128 ? bq[i] : (i < 256 ? bk[i - 128] : bv[i - 256]);
            return;
        }
        const float* W; __hip_bfloat16* Wt; int K, N, idx;
        if (t < 65536) {
            int which = t >> 14; idx = t & 16383; K = 128; N = 128;
            W = which == 0 ? Wq : which == 1 ? Wk : which == 2 ? Wv : Wo;
            Wt = which == 3 ? Wot : Wqkvt + which * 16384;
        } else if (t < 131072) { idx = t - 65536;  K = 128; N = 512; W = W1; Wt = W1t; }
        else                   { idx = t - 131072; K = 512; N = 128; W = W2; Wt = W2t; }
        int n = idx / K, k = idx - n * K;
        Wt[idx] = __float2bfloat16(W[(size_t)k * N + n]);
    } else {
        int wave = tid >> 6;
        int lane = tid & 63;
        int row = (b - BINA_BLOCKS - WCVT_BLOCKS) * 4 + wave;
        if (row >= N_NODES) return;
        float2 v = ((const float2*)(x + (size_t)row * HID))[lane];
        float s = wave_reduce_sum(v.x + v.y);
        float mu = s * (1.0f / HID);
        float dx = v.x - mu, dy = v.y - mu;
        float q = wave_reduce_sum(dx * dx + dy * dy);
        float rstd = rsqrtf(q * (1.0f / HID) + 1e-5f);
        float2 gg = ((const float2*)g1)[lane];
        float2 bb = ((const float2*)be1)[lane];
        __hip_bfloat162 o;
        o.x = __float2bfloat16(dx * rstd * gg.x + bb.x);
        o.y = __float2bfloat16(dy * rstd * gg.y + bb.y);
        ((__hip_bfloat162*)(h_out + (size_t)row * HID))[lane] = o;
    }
}

// ================= merged kernel: binB (first 196 blocks) + QKV GEMM (rest) =========
__global__ __launch_bounds__(512) void qkv_binb_kernel(
    const int* __restrict__ bcur, const unsigned int* __restrict__ temp,
    unsigned int* __restrict__ packed, int* __restrict__ offs,
    const __hip_bfloat16* __restrict__ A, const __hip_bfloat16* __restrict__ Wt,
    const float* __restrict__ bias,
    _Float16* __restrict__ Chh, unsigned char* __restrict__ C8, int M) {
    __shared__ short8 smem[2048 + 2048];  // 64KB; binB aliases first 3KB
    const int tid = threadIdx.x;
    if (blockIdx.x < NBKT) {
        int* cnts = (int*)smem;
        int* hist = cnts + 256;
        int* cur = hist + 256;
        const int b = blockIdx.x;
        if (tid < 256) {
            cnts[tid] = (tid < NBKT) ? bcur[tid] : 0;
            hist[tid] = 0;
        }
        __syncthreads();
        for (int off = 1; off < 256; off <<= 1) {
            int x = 0;
            if (tid < 256 && tid >= off) x = cnts[tid - off];
            __syncthreads();
            if (tid < 256) cnts[tid] += x;
            __syncthreads();
        }
        const int cnt = bcur[b];
        const int start = cnts[b] - cnt;
        const size_t base = (size_t)b * BKT_CAP;
        for (int i = tid; i < cnt; i += 512)
            atomicAdd(&hist[(temp[base + i] >> 20) & 255], 1);
        __syncthreads();
        if (tid < 256) cur[tid] = hist[tid];
        __syncthreads();
        for (int off = 1; off < 256; off <<= 1) {
            int x = 0;
            if (tid < 256 && tid >= off) x = cur[tid - off];
            __syncthreads();
            if (tid < 256) cur[tid] += x;
            __syncthreads();
        }
        const int node0 = b * 256;
        if (tid < 256) {
            int excl = cur[tid] - hist[tid];
            cur[tid] = excl;
            int node = node0 + tid;
            if (node < N_NODES) offs[node] = start + excl;
        }
        if (b == NBKT - 1 && tid == 0) offs[N_NODES] = start + cnt;
        __syncthreads();
        for (int i = tid; i < cnt; i += 512) {
            unsigned int v = temp[base + i];
            int d = (v >> 20) & 255;
            int p = start + atomicAdd(&cur[d], 1);
            packed[p] = v & 0xFFFFFu;   // src | attr<<16
        }
        return;
    }
    // ---- QKV GEMM part ----
    const int gb = blockIdx.x - NBKT;
    const int plane = gb / QKV_XBLOCKS;
    const int xb = gb - plane * QKV_XBLOCKS;
    const int row0 = xb * 128;
    const int col0 = plane * 128;
    const int w = tid >> 6, l = tid & 63;
    const int lr = l & 15, hi = l >> 4;
    f32x4 acc[8] = {};
    #pragma unroll
    for (int it = 0; it < 4; ++it) {
        unsigned d = tid + it * 512;
        int r = d >> 4, sd = d & 15;
        int ss = sd ^ (r & 7);
        int gr = row0 + r; if (gr >= M) gr = M - 1;
        __builtin_amdgcn_global_load_lds(
            (const __attribute__((address_space(1))) void*)(A + (size_t)gr * 128 + ss * 8),
            (__attribute__((address_space(3))) void*)(smem + (d & ~63u)),
            16, 0, 0);
    }
    #pragma unroll
    for (int it = 0; it < 4; ++it) {
        unsigned d = tid + it * 512;
        int r = d >> 4, sd = d & 15;
        int ss = sd ^ (r & 7);
        __builtin_amdgcn_global_load_lds(
            (const __attribute__((address_space(1))) void*)(Wt + (size_t)(col0 + r) * 128 + ss * 8),
            (__attribute__((address_space(3))) void*)(smem + 2048 + (d & ~63u)),
            16, 0, 0);
    }
    __syncthreads();
    const int ar = w * 16 + lr;
    #pragma unroll
    for (int ks = 0; ks < 4; ++ks) {
        int s = ks * 4 + hi;
        short8 a = smem[ar * 16 + (s ^ (ar & 7))];
        #pragma unroll
        for (int f = 0; f < 8; ++f) {
            int br = f * 16 + lr;
            short8 b = smem[2048 + br * 16 + (s ^ (br & 7))];
            acc[f] = __builtin_amdgcn_mfma_f32_16x16x32_bf16(a, b, acc[f], 0, 0, 0);
        }
    }
    const float scl = (plane == 0) ? 0.25f : 1.0f;
    #pragma unroll
    for (int f = 0; f < 8; ++f) {
        int c = col0 + f * 16 + lr;
        float bv = bias[c];
        #pragma unroll
        for (int j = 0; j < 4; ++j) {
            int r = row0 + w * 16 + hi * 4 + j;
            if (r < M) {
                float v = acc[f][j] + bv;
                if (plane < 2)
                    Chh[(size_t)plane * N_NODES * 128 + (size_t)r * 128 + (c & 127)] =
                        (_Float16)(v * scl);
                else
                    C8[(size_t)r * 128 + (c & 127)] = fp8e(v);
            }
        }
    }
}

// ===== Fused tail: Wo GEMM + residual(x) + LN2 + FFN1 + relu + FFN2 + residual =====
// 32 rows/block, 256 thr (4 waves). Wave w: rt=w&1 (16-row half), ch=w>>1 (64-col half).
// hseg: attn_ob tile then h2 tile (8KB). wseg: Wot then f1 tile (32KB).
// bseg: DOUBLE-BUFFERED 2x16KB weight staging (stage c+1 overlaps compute c, 1 barrier/chunk).
// x1 kept in REGISTERS (f32) for the final residual.
__global__ __launch_bounds__(256) void tail_kernel(
    const __hip_bfloat16* __restrict__ attn_ob,  // [N][128]
    const __hip_bfloat16* __restrict__ Wot,      // [128][128]
    const float* __restrict__ bo,
    const float* __restrict__ x,                 // [N][128] f32
    const float* __restrict__ g2, const float* __restrict__ be2,
    const __hip_bfloat16* __restrict__ W1t,      // [512][128]
    const float* __restrict__ b1,
    const __hip_bfloat16* __restrict__ W2t,      // [128][512]
    const float* __restrict__ b2,
    float* __restrict__ outp, int M) {
    __shared__ short8 hseg[32 * 16];     // 8KB
    __shared__ short8 wseg[2048];        // 32KB
    __shared__ short8 bseg[2][1024];     // 2x16KB double buffer
    __shared__ float lnS[2][32];
    __shared__ float lnQ[2][32];
    const int tid = threadIdx.x;
    const int row0 = blockIdx.x * 32;
    const int w = tid >> 6, l = tid & 63;
    const int lr = l & 15, hi = l >> 4;
    const int rt = w & 1, ch = w >> 1;
    // stage attn_ob tile (512 segs)
    #pragma unroll
    for (int it = 0; it < 2; ++it) {
        unsigned d = tid + it * 256;
        int r = d >> 4, sd = d & 15;
        int ss = sd ^ (r & 7);
        int gr = row0 + r; if (gr >= M) gr = M - 1;
        __builtin_amdgcn_global_load_lds(
            (const __attribute__((address_space(1))) void*)(attn_ob + (size_t)gr * 128 + ss * 8),
            (__attribute__((address_space(3))) void*)(hseg + (d & ~63u)),
            16, 0, 0);
    }
    // stage Wot (2048 segs)
    #pragma unroll
    for (int it = 0; it < 8; ++it) {
        unsigned d = tid + it * 256;
        int r = d >> 4, sd = d & 15;
        int ss = sd ^ (r & 7);
        __builtin_amdgcn_global_load_lds(
            (const __attribute__((address_space(1))) void*)(Wot + (size_t)r * 128 + ss * 8),
            (__attribute__((address_space(3))) void*)(wseg + (d & ~63u)),
            16, 0, 0);
    }
    // prefetch FFN1 chunk 0 into bseg[0]
    #pragma unroll
    for (int it = 0; it < 4; ++it) {
        unsigned d = tid + it * 256;
        int rb = d >> 4, sd = d & 15;
        int ss = sd ^ (rb & 7);
        __builtin_amdgcn_global_load_lds(
            (const __attribute__((address_space(1))) void*)(W1t + (size_t)rb * 128 + ss * 8),
            (__attribute__((address_space(3))) void*)(bseg[0] + (d & ~63u)),
            16, 0, 0);
    }
    __syncthreads();
    // Wo GEMM: wave covers rows rt*16..+15, cols ch*64..+63
    const int ar = rt * 16 + lr;
    f32x4 acc[4] = {};
    #pragma unroll
    for (int ks = 0; ks < 4; ++ks) {
        int s = ks * 4 + hi;
        short8 a = hseg[ar * 16 + (s ^ (ar & 7))];
        #pragma unroll
        for (int f = 0; f < 4; ++f) {
            int br = ch * 64 + f * 16 + lr;
            short8 b = wseg[br * 16 + (s ^ (br & 7))];
            acc[f] = __builtin_amdgcn_mfma_f32_16x16x32_bf16(a, b, acc[f], 0, 0, 0);
        }
    }
    // x1 = acc + bo + x residual (kept in registers)
    float vv[4][4];
    float gc[4], bc[4];
    #pragma unroll
    for (int f = 0; f < 4; ++f) {
        int c = ch * 64 + f * 16 + lr;
        gc[f] = g2[c]; bc[f] = be2[c];
        float bv = bo[c];
        #pragma unroll
        for (int j = 0; j < 4; ++j) {
            int r = row0 + rt * 16 + hi * 4 + j;
            int rr = r < M ? r : M - 1;
            vv[f][j] = acc[f][j] + bv + x[(size_t)rr * 128 + c];
        }
    }
    // LN2 partials over this wave's 64 cols
    float ps[4], pq[4];
    #pragma unroll
    for (int j = 0; j < 4; ++j) {
        float s = 0.f, q = 0.f;
        #pragma unroll
        for (int f = 0; f < 4; ++f) { s += vv[f][j]; q += vv[f][j] * vv[f][j]; }
        #pragma unroll
        for (int m = 1; m <= 8; m <<= 1) { s += __shfl_xor(s, m); q += __shfl_xor(q, m); }
        ps[j] = s; pq[j] = q;
    }
    if (lr == 0) {
        #pragma unroll
        for (int j = 0; j < 4; ++j) {
            int r = rt * 16 + hi * 4 + j;
            lnS[ch][r] = ps[j];
            lnQ[ch][r] = pq[j];
        }
    }
    __syncthreads();
    // combine halves; write h2 bf16 into hseg (overwrites attn_ob tile)
    unsigned short* hu = (unsigned short*)hseg;
    #pragma unroll
    for (int j = 0; j < 4; ++j) {
        int r = rt * 16 + hi * 4 + j;
        float s = lnS[0][r] + lnS[1][r];
        float q = lnQ[0][r] + lnQ[1][r];
        float mu = s * (1.0f / 128.0f);
        float rstd = rsqrtf(q * (1.0f / 128.0f) - mu * mu + 1e-5f);
        #pragma unroll
        for (int f = 0; f < 4; ++f) {
            int c = ch * 64 + f * 16 + lr;
            int seg = c >> 3;
            float hv = (vv[f][j] - mu) * rstd * gc[f] + bc[f];
            hu[r * 128 + ((seg ^ (r & 7)) << 3) + (c & 7)] = bf16u(hv);
        }
    }
    __syncthreads();
    // FFN1: 8 chunks of 64 out-cols; f1 tile into wseg (Wot dead).
    // Pipeline: stage(c+1) issued before compute(c); single barrier per chunk.
    unsigned short* f1u = (unsigned short*)wseg;
    for (int cc = 0; cc < 8; ++cc) {
        if (cc + 1 < 8) {
            short8* dst = bseg[(cc + 1) & 1];
            #pragma unroll
            for (int it = 0; it < 4; ++it) {
                unsigned d = tid + it * 256;
                int rb = d >> 4, sd = d & 15;
                int ss = sd ^ (rb & 7);
                __builtin_amdgcn_global_load_lds(
                    (const __attribute__((address_space(1))) void*)(W1t + (size_t)((cc + 1) * 64 + rb) * 128 + ss * 8),
                    (__attribute__((address_space(3))) void*)(dst + (d & ~63u)),
                    16, 0, 0);
            }
        } else {
            // prefetch FFN2 chunk 0 into bseg[0] (bseg[0] last read at cc=6; barrier since)
            #pragma unroll
            for (int it = 0; it < 4; ++it) {
                unsigned d = tid + it * 256;
                int rb = d >> 3, sd = d & 7;
                int ss = sd ^ (rb & 7);
                __builtin_amdgcn_global_load_lds(
                    (const __attribute__((address_space(1))) void*)(W2t + (size_t)rb * 512 + ss * 8),
                    (__attribute__((address_space(3))) void*)(bseg[0] + (d & ~63u)),
                    16, 0, 0);
            }
        }
        const short8* cur = bseg[cc & 1];
        f32x4 a0 = {}, a1 = {};
        #pragma unroll
        for (int ks = 0; ks < 4; ++ks) {
            int s = ks * 4 + hi;
            short8 a = hseg[ar * 16 + (s ^ (ar & 7))];
            int rb0 = ch * 32 + lr;
            short8 b0 = cur[rb0 * 16 + (s ^ (rb0 & 7))];
            a0 = __builtin_amdgcn_mfma_f32_16x16x32_bf16(a, b0, a0, 0, 0, 0);
            int rb1 = ch * 32 + 16 + lr;
            short8 b1v = cur[rb1 * 16 + (s ^ (rb1 & 7))];
            a1 = __builtin_amdgcn_mfma_f32_16x16x32_bf16(a, b1v, a1, 0, 0, 0);
        }
        #pragma unroll
        for (int f = 0; f < 2; ++f) {
            int c = cc * 64 + ch * 32 + f * 16 + lr;    // 0..511
            float bv = b1[c];
            int seg = c >> 3;
            #pragma unroll
            for (int j = 0; j < 4; ++j) {
                int r = rt * 16 + hi * 4 + j;
                float v = fmaxf((f == 0 ? a0[j] : a1[j]) + bv, 0.f);
                f1u[r * 512 + ((seg ^ (r & 7)) << 3) + (c & 7)] = bf16u(v);
            }
        }
        __syncthreads();   // next buf loads done + f1 writes visible
    }
    // FFN2: K=512 in 8 chunks of 64; same pipeline.
    f32x4 acc2[4] = {};
    for (int kc = 0; kc < 8; ++kc) {
        if (kc + 1 < 8) {
            short8* dst = bseg[(kc + 1) & 1];
            #pragma unroll
            for (int it = 0; it < 4; ++it) {
                unsigned d = tid + it * 256;
                int rb = d >> 3, sd = d & 7;
                int ss = sd ^ (rb & 7);
                __builtin_amdgcn_global_load_lds(
                    (const __attribute__((address_space(1))) void*)(W2t + (size_t)rb * 512 + (kc + 1) * 64 + ss * 8),
                    (__attribute__((address_space(3))) void*)(dst + (d & ~63u)),
                    16, 0, 0);
            }
        }
        const short8* cur = bseg[kc & 1];
        #pragma unroll
        for (int ks = 0; ks < 2; ++ks) {
            int ksg = kc * 8 + ks * 4 + hi;             // global k-seg 0..63
            short8 a = *(const short8*)&f1u[ar * 512 + ((ksg ^ (ar & 7)) << 3)];
            int s2 = ks * 4 + hi;
            #pragma unroll
            for (int f = 0; f < 4; ++f) {
                int rb = ch * 64 + f * 16 + lr;
                short8 b = cur[rb * 8 + (s2 ^ (rb & 7))];
                acc2[f] = __builtin_amdgcn_mfma_f32_16x16x32_bf16(a, b, acc2[f], 0, 0, 0);
            }
        }
        __syncthreads();
    }
    // epilogue: + b2 + x1 (register, f32) -> out
    #pragma unroll
    for (int f = 0; f < 4; ++f) {
        int c = ch * 64 + f * 16 + lr;
        float bv = b2[c];
        #pragma unroll
        for (int j = 0; j < 4; ++j) {
            int r = row0 + rt * 16 + hi * 4 + j;
            if (r < M)
                outp[(size_t)r * 128 + c] = acc2[f][j] + bv + vv[f][j];
        }
    }
}

// ---------------- Fused edge phase: persistent waves, STATIC grid-stride ------
// Q,K: f16 planes [2][N][128] (Q pre-scaled 1/sqrt(D)); V: fp8 plane [N][128].
// Grid-stride keeps all active waves in one contiguous node window (hot L2 slice
// of packed/Q/out) -- measured faster than edge-balanced contiguous ranges (R17).
__global__ __launch_bounds__(256) void fused_attn_kernel(
    const unsigned int* __restrict__ packed,
    const int* __restrict__ offs,
    const _Float16* __restrict__ qkh,   // [2][N][128]
    const unsigned char* __restrict__ v8p,  // [N][128]
    const float* __restrict__ btab,     // [13,8]
    __hip_bfloat16* __restrict__ out) {
    __shared__ float bLDS[104];
    const int tid = threadIdx.x;
    if (tid < 104) bLDS[tid] = btab[tid];
    __syncthreads();
    const int wave = tid >> 6, lane = tid & 63;
    const int slot = lane >> 3, sub = lane & 7;
    const char* qh = (const char*)qkh;
    const unsigned sb = (unsigned)sub << 5;
    const char* khs = (const char*)(qkh + (size_t)N_NODES * 128) + sb;
    const unsigned char* v8s = v8p + (sb >> 1);
    const unsigned gwave = blockIdx.x * 4 + wave;
    const unsigned stride = ATTN_BLOCKS * 4;
    for (unsigned n = gwave; n < N_NODES; n += stride) {
        U4H q0, q1;
        q0.u = *(const uint4*)(qh + (n << 8) + sb);
        q1.u = *(const uint4*)(qh + (n << 8) + sb + 16u);
        const int lo = offs[n], hi = offs[n + 1];
        const int nit = (hi - lo + 7) >> 3;
        f32x2 acc2[8] = {};
        float wsum = 0.f;
        int i = lo + slot;
        bool vd0 = i < hi;       unsigned pk0 = vd0 ? packed[i] : 0u;
        bool vd1 = i + 8 < hi;   unsigned pk1 = vd1 ? packed[i + 8] : 0u;
        KV a = loadkv(khs, v8s, pk0);
        KV b = loadkv(khs, v8s, pk1);
        int ii = i + 16;
        int rem = nit;
        while (rem >= 2) {
            const bool vd2 = ii < hi;
            const unsigned pk2 = vd2 ? packed[ii] : 0u;
            const bool vd3 = ii + 8 < hi;
            const unsigned pk3 = vd3 ? packed[ii + 8] : 0u;
            consume_kv(a, pk0, vd0, q0, q1, bLDS, sub, acc2, wsum);
            a = loadkv(khs, v8s, pk2);
            consume_kv(b, pk1, vd1, q0, q1, bLDS, sub, acc2, wsum);
            b = loadkv(khs, v8s, pk3);
            pk0 = pk2; vd0 = vd2;
            pk1 = pk3; vd1 = vd3;
            ii += 16;
            rem -= 2;
        }
        if (rem == 1) consume_kv(a, pk0, vd0, q0, q1, bLDS, sub, acc2, wsum);
        float accf[16];
        #pragma unroll
        for (int j = 0; j < 8; ++j) { accf[2 * j] = acc2[j][0]; accf[2 * j + 1] = acc2[j][1]; }
        #pragma unroll
        for (int j = 0; j < 16; ++j) {
            accf[j] += __shfl_xor(accf[j], 8);
            accf[j] += __shfl_xor(accf[j], 16);
            accf[j] += __shfl_xor(accf[j], 32);
        }
        wsum += __shfl_xor(wsum, 8);
        wsum += __shfl_xor(wsum, 16);
        wsum += __shfl_xor(wsum, 32);
        if (slot == 0) {
            float inv = 1.0f / (wsum + 1e-8f);
            uint4 o0, o1;
            o0.x = packbf2(accf[0] * inv, accf[1] * inv);
            o0.y = packbf2(accf[2] * inv, accf[3] * inv);
            o0.z = packbf2(accf[4] * inv, accf[5] * inv);
            o0.w = packbf2(accf[6] * inv, accf[7] * inv);
            o1.x = packbf2(accf[8] * inv, accf[9] * inv);
            o1.y = packbf2(accf[10] * inv, accf[11] * inv);
            o1.z = packbf2(accf[12] * inv, accf[13] * inv);
            o1.w = packbf2(accf[14] * inv, accf[15] * inv);
            char* op = (char*)out + (n << 8) + ((unsigned)sub << 5);
            *(uint4*)op = o0;
            *(uint4*)(op + 16) = o1;
        }
    }
}

extern "C" void kernel_launch(void* const* d_in, const int* in_sizes, int n_in,
                              void* d_out, int out_size, void* d_ws, size_t ws_size,
                              hipStream_t stream) {
    const float* x    = (const float*)d_in[0];
    const int*   ei   = (const int*)d_in[1];
    const int*   attr = (const int*)d_in[2];
    const float* Wq   = (const float*)d_in[3];
    const float* bq   = (const float*)d_in[4];
    const float* Wk   = (const float*)d_in[5];
    const float* bk   = (const float*)d_in[6];
    const float* Wv   = (const float*)d_in[7];
    const float* bv   = (const float*)d_in[8];
    const float* Wo   = (const float*)d_in[9];
    const float* bo   = (const float*)d_in[10];
    const float* ebt  = (const float*)d_in[11];
    const float* W1   = (const float*)d_in[12];
    const float* b1   = (const float*)d_in[13];
    const float* W2   = (const float*)d_in[14];
    const float* b2   = (const float*)d_in[15];
    const float* g1   = (const float*)d_in[16];
    const float* be1  = (const float*)d_in[17];
    const float* g2   = (const float*)d_in[18];
    const float* be2  = (const float*)d_in[19];
    float* out = (float*)d_out;

    char* ws = (char*)d_ws;
    const size_t szRowB = (size_t)N_NODES * HID * 2;   // 12.8 MB
    const size_t ALIGN = 256;
    #define ALN(v) (((v) + ALIGN - 1) & ~(ALIGN - 1))
    size_t o = 0;
    __hip_bfloat16* h_buf = (__hip_bfloat16*)(ws + o); o += szRowB;
    _Float16* QKh = (_Float16*)(ws + o); o += (size_t)N_NODES * 256 * 2;        // 25.6MB (Q+K f16)
    unsigned char* V8 = (unsigned char*)(ws + o); o += (size_t)N_NODES * 128;   // 6.4MB
    unsigned int* packed = (unsigned int*)(ws + o); o += (size_t)E_EDGES * 4;   // 6.4MB
    unsigned int* temp = (unsigned int*)(ws + o); o += (size_t)NBKT * BKT_CAP * 4; // 7.2MB
    int* bcur = (int*)(ws + o); o = ALN(o + (size_t)NBKT * 4);
    int* offs = (int*)(ws + o); o = ALN(o + (size_t)(N_NODES + 1) * 4);
    __hip_bfloat16* attn_ob = (__hip_bfloat16*)(ws + o); o += szRowB;
    __hip_bfloat16* Wqkvt = (__hip_bfloat16*)(ws + o); o += 384 * 128 * 2;
    __hip_bfloat16* Wot = (__hip_bfloat16*)(ws + o); o += 128 * 128 * 2;
    __hip_bfloat16* W1t = (__hip_bfloat16*)(ws + o); o += 512 * 128 * 2;
    __hip_bfloat16* W2t = (__hip_bfloat16*)(ws + o); o += 128 * 512 * 2;
    float* bqkv = (float*)(ws + o); o += 384 * 4;       // ~60 MB total

    hipMemsetAsync(bcur, 0, (size_t)NBKT * 4, stream);

    // Stage 1: binA + weight converts + LN1 co-scheduled in one launch
    prep_kernel<<<BINA_BLOCKS + WCVT_BLOCKS + LN_BLOCKS, 256, 0, stream>>>(
        ei, attr, bcur, temp,
        Wq, Wk, Wv, Wo, W1, W2, bq, bk, bv,
        Wqkvt, Wot, W1t, W2t, bqkv,
        x, g1, be1, h_buf);

    // Stage 2: binB (196 blocks) + QKV GEMM (391x3 blocks) in one launch
    qkv_binb_kernel<<<NBKT + QKV_XBLOCKS * 3, 512, 0, stream>>>(
        bcur, temp, packed, offs,
        h_buf, Wqkvt, bqkv, QKh, V8, N_NODES);

    // Fused edge phase: grid-stride persistent waves; Q/K f16, V fp8
    fused_attn_kernel<<<ATTN_BLOCKS, 256, 0, stream>>>(packed, offs, QKh, V8, ebt, attn_ob);

    // Fused tail: Wo + residual + LN2 + FFN1 + FFN2 + residual, one kernel (dbuf staging)
    tail_kernel<<<(N_NODES + 31) / 32, 256, 0, stream>>>(
        attn_ob, Wot, bo, x, g2, be2, W1t, b1, W2t, b2, out, N_NODES);
}